// Round 1
// baseline (83.352 us; speedup 1.0000x reference)
//
#include <hip/hip_runtime.h>

namespace {
constexpr int P     = 4096;           // 16*16*16 voxels
constexpr int KC    = 4;              // label channels
constexpr int NS    = 81;             // (di,dj) pairs with di^2+dj^2 <= 25
constexpr int NGRP  = 27;             // 27 groups of 3 slices: s = g + 27*sub
constexpr int BLOCK = 256;
constexpr int PBLK  = P / BLOCK;      // 16 p-blocks per (n, group)
constexpr int BLK_N = NGRP * PBLK;    // 432 blocks per n
constexpr int NBLK  = 2 * BLK_N;      // 864 total

struct Tab {
    signed char di[NS], dj[NS], ir[NS], sq2[NS];
};
constexpr Tab make_tab() {
    Tab t{};
    int idx = 0;
    for (int a = -5; a <= 5; ++a)
        for (int b = -5; b <= 5; ++b) {
            int s2 = a * a + b * b;
            if (s2 <= 25) {
                t.di[idx] = (signed char)a;
                t.dj[idx] = (signed char)b;
                int rem = 25 - s2, r = 0;
                while ((r + 1) * (r + 1) <= rem) ++r;
                t.ir[idx]  = (signed char)r;
                t.sq2[idx] = (signed char)s2;
                ++idx;
            }
        }
    return t;
}
}

__device__ constexpr Tab TAB = make_tab();

// Partials + completion counter live in __device__ globals: d_ws is unused
// (the harness poison-fills it regardless; we just stop depending on it).
// g_count self-resets in the last block, so repeated graph replays are safe.
__device__ float g_partials[NBLK * 8];
__device__ int   g_count = 0;

// One fused dispatch. Thread = (n, group, p): each thread handles the 3
// slices s = g + 27*sub (interleaved across the TAB 'a' bands for load
// balance), sharing one accumulator set -- per-thread setup and the 48-op
// wave reduction are amortized 3x vs the previous 2592-block version.
// Total inner-loop work is unchanged. The block that finishes last does the
// finalize (device-scope release/acquire via threadfence + atomic counter).
__global__ __launch_bounds__(BLOCK) void sncut_fused(
        const float* __restrict__ labels,
        const float* __restrict__ inputs,
        float* __restrict__ out) {
    const int b  = blockIdx.x;
    const int n  = (b >= BLK_N) ? 1 : 0;
    const int lb = b - n * BLK_N;         // [0, 432)
    const int g  = lb >> 4;               // group   [0, 27)  (uniform/block)
    const int pb = lb & 15;               // p-block [0, 16)  (uniform/block)
    const int p  = pb * BLOCK + threadIdx.x;

    const int i  = p >> 8;                // == pb, uniform per block
    const int j  = (p >> 4) & 15;
    const int kz = p & 15;

    const float* __restrict__ inp = inputs + n * P;
    const float* __restrict__ A   = labels + n * KC * P;

    const float Ip = inp[p];

    float s_w = 0.f, s_k0 = 0.f, s_k1 = 0.f, s_k2 = 0.f, s_k3 = 0.f;

    #pragma unroll
    for (int sub = 0; sub < 3; ++sub) {
        const int s   = g + NGRP * sub;   // uniform per block -> scalar loads
        const int di  = TAB.di[s];
        const int dj  = TAB.dj[s];
        const int ir  = TAB.ir[s];
        const int sq2 = TAB.sq2[s];

        const int ii = i + di;            // uniform per block
        const int jj = j + dj;

        if ((unsigned)ii < 16u && (unsigned)jj < 16u) {
            const int base = p + di * 256 + dj * 16;
            const int lo   = (-kz > -ir) ? -kz : -ir;
            const int hi   = (15 - kz < ir) ? (15 - kz) : ir;
            for (int dk = lo; dk <= hi; ++dk) {
                const int   q = base + dk;
                const float d = Ip - inp[q];
                // exp(-sqd/4 - (Ip-Iq)^2/10)
                const float w = __expf(-0.25f * (float)(sq2 + dk * dk)
                                       - 0.1f * d * d);
                s_w  += w;
                s_k0 += w * A[q];
                s_k1 += w * A[P + q];
                s_k2 += w * A[2 * P + q];
                s_k3 += w * A[3 * P + q];
            }
        }
    }

    float vals[8];
    {
        const float a0 = A[p];
        const float a1 = A[P + p];
        const float a2 = A[2 * P + p];
        const float a3 = A[3 * P + p];
        vals[0] = a0 * s_k0;   // numerator partials
        vals[1] = a1 * s_k1;
        vals[2] = a2 * s_k2;
        vals[3] = a3 * s_k3;
        vals[4] = a0 * s_w;    // denominator partials (symmetry of W)
        vals[5] = a1 * s_w;
        vals[6] = a2 * s_w;
        vals[7] = a3 * s_w;
    }

    // 64-lane wave reduction (block lies entirely within one n)
    #pragma unroll
    for (int off = 32; off >= 1; off >>= 1) {
        #pragma unroll
        for (int t = 0; t < 8; ++t)
            vals[t] += __shfl_down(vals[t], off, 64);
    }

    __shared__ float red[4][8];
    __shared__ bool  is_last;
    const int lane = threadIdx.x & 63;
    const int wid  = threadIdx.x >> 6;
    if (lane == 0) {
        #pragma unroll
        for (int t = 0; t < 8; ++t) red[wid][t] = vals[t];
    }
    __syncthreads();

    // Thread 0 performs ALL 8 global partial stores, then release-fences and
    // bumps the counter (release ordering of its own stores is sufficient).
    if (threadIdx.x == 0) {
        #pragma unroll
        for (int t = 0; t < 8; ++t)
            g_partials[b * 8 + t] =
                red[0][t] + red[1][t] + red[2][t] + red[3][t];
        __threadfence();
        is_last = (atomicAdd(&g_count, 1) == NBLK - 1);
    }
    __syncthreads();

    if (is_last) {
        __threadfence();                   // acquire: all blocks' partials visible
        __shared__ float sm[2][256];
        const int t  = threadIdx.x;
        const int c  = t & 7;
        const int g2 = t >> 3;             // 32 strided groups
        float a0 = 0.f, a1 = 0.f;
        for (int bb = g2; bb < NBLK; bb += 32) {
            const float v = g_partials[bb * 8 + c];
            if (bb < BLK_N) a0 += v; else a1 += v;
        }
        sm[0][t] = a0;
        sm[1][t] = a1;
        __syncthreads();
        if (t < 16) {
            const int nn = t >> 3, cc = t & 7;
            float sacc = 0.f;
            for (int k = 0; k < 32; ++k) sacc += sm[nn][cc + 8 * k];
            sm[nn][cc] = sacc;
        }
        __syncthreads();
        if (t < 2) {
            float loss = 0.f;
            #pragma unroll
            for (int k = 0; k < 4; ++k)
                loss += sm[t][k] / (sm[t][4 + k] + 1e-8f);
            out[t] = (float)KC - loss;
        }
        if (t == 0) atomicExch(&g_count, 0);   // reset for next graph replay
    }
}

extern "C" void kernel_launch(void* const* d_in, const int* in_sizes, int n_in,
                              void* d_out, int out_size, void* d_ws, size_t ws_size,
                              hipStream_t stream) {
    const float* labels = (const float*)d_in[0];   // (2,4,16,16,16)
    const float* inputs = (const float*)d_in[1];   // (2,1,16,16,16)
    float* out = (float*)d_out;                    // (2,) float32
    (void)d_ws; (void)ws_size;

    hipLaunchKernelGGL(sncut_fused, dim3(NBLK), dim3(BLOCK), 0, stream,
                       labels, inputs, out);
}